// Round 5
// baseline (314.673 us; speedup 1.0000x reference)
//
#include <hip/hip_runtime.h>

typedef __bf16 bf16x8 __attribute__((ext_vector_type(8)));
typedef __bf16 bf16x4 __attribute__((ext_vector_type(4)));
typedef float  f32x4  __attribute__((ext_vector_type(4)));
typedef float  f32x2  __attribute__((ext_vector_type(2)));

constexpr int BATCH = 65536;
constexpr int OBS   = 20;
constexpr int PRED  = 12;
constexpr int BT    = 64;    // batch rows per workgroup -> grid 1024 = 4 blocks/CU, all resident
constexpr int AST   = 136;   // A-row stride in bf16 elems

// gate pre-scales folded into weights/biases:
// i,f,o scaled by -log2(e)  -> sigmoid(x) = rcp(1 + exp2(gate))
// g     scaled by +2*log2(e)-> tanh(x)    = (exp2(gate)-1)/(exp2(gate)+1)
constexpr float SIO = -1.4426950408889634f;
constexpr float SG  =  2.8853900817779268f;

__device__ __forceinline__ float exp2_(float x) { return __builtin_amdgcn_exp2f(x); }
__device__ __forceinline__ float rcp_(float x)  { return __builtin_amdgcn_rcpf(x); }

struct SmallW {
    float  biasf_e[256];  // prescaled, fragment-ordered: [(wv*4+c)*16 + q*4 + r]
    float  biasf_d[256];
    float4 embc[64];      // {w_emb[e][0], w_emb[e][1], b_emb[e], 0}
    float  wfc[128];      // W_fc [2][64]
    float  bfc[2];
};

__global__ __launch_bounds__(256, 4)
void vanilla_lstm(const float* __restrict__ obs,
                  const float* __restrict__ W_emb, const float* __restrict__ b_emb,
                  const float* __restrict__ Wih_e, const float* __restrict__ Whh_e,
                  const float* __restrict__ bih_e, const float* __restrict__ bhh_e,
                  const float* __restrict__ Wih_d, const float* __restrict__ Whh_d,
                  const float* __restrict__ bih_d, const float* __restrict__ bhh_d,
                  const float* __restrict__ W_fc,  const float* __restrict__ b_fc,
                  float* __restrict__ out)
{
    __shared__ __align__(16) __bf16 As[BT * AST];   // [x(64) | h(64)] bf16, padded
    __shared__ bf16x8 wkt3[1024];                   // Whh cols 32..63, fragment-ordered, 16 KB
    __shared__ __align__(16) float  pred_s[BT * 2];
    __shared__ SmallW sw;

    const int tid  = threadIdx.x;
    const int wv   = tid >> 6;
    const int lane = tid & 63;
    const int m    = lane & 15;
    const int q    = lane >> 4;
    const int wblk = wv * 16;          // this wave's 16 hidden cols
    const size_t gRow0 = (size_t)blockIdx.x * BT;

    // ---- stage small weights ----
    {
        const int wv_ = tid >> 6, c_ = (tid >> 4) & 3, qr = tid & 15;
        const int g = c_ * 64 + wv_ * 16 + qr;
        const float sc = (c_ == 2) ? SG : SIO;
        sw.biasf_e[tid] = sc * (bih_e[g] + bhh_e[g]);
        sw.biasf_d[tid] = sc * (bih_d[g] + bhh_d[g]);
    }
    if (tid < 64)  sw.embc[tid] = make_float4(W_emb[2 * tid], W_emb[2 * tid + 1], b_emb[tid], 0.f);
    if (tid < 128) sw.wfc[tid]  = W_fc[tid];
    if (tid < 2)   sw.bfc[tid]  = b_fc[tid];

    // ---- zero As (h half must start at 0) ----
    {
        uint4 z; z.x = z.y = z.z = z.w = 0u;
        uint4* p = (uint4*)As;
        constexpr int NV = BT * AST * 2 / 16;   // 1088
        #pragma unroll
        for (int i = 0; i < NV / 256; ++i) p[tid + i * 256] = z;
        if (tid < (NV % 256)) p[tid + (NV / 256) * 256] = z;
    }

    // ---- weight fragments: kt 0..2 in regs, kt 3 in LDS (wave-local slice) ----
    bf16x8 bfr[4][3];
    auto load_bfr = [&](const float* Wih, const float* Whh) {
        #pragma unroll
        for (int c = 0; c < 4; ++c) {
            const float sc = (c == 2) ? SG : SIO;
            const int n = c * 64 + wblk + m;
            #pragma unroll
            for (int kt = 0; kt < 3; ++kt) {
                const float* s = (kt < 2) ? (Wih + n * 64 + kt * 32 + q * 8)
                                          : (Whh + n * 64 + q * 8);
                float4 a = *(const float4*)s;
                float4 b = *(const float4*)(s + 4);
                bf16x8 v;
                v[0] = (__bf16)(sc * a.x); v[1] = (__bf16)(sc * a.y);
                v[2] = (__bf16)(sc * a.z); v[3] = (__bf16)(sc * a.w);
                v[4] = (__bf16)(sc * b.x); v[5] = (__bf16)(sc * b.y);
                v[6] = (__bf16)(sc * b.z); v[7] = (__bf16)(sc * b.w);
                bfr[c][kt] = v;
            }
        }
    };
    auto fill_wkt3 = [&](const float* Whh) {   // wave-local slice only -> no cross-wave hazard
        #pragma unroll
        for (int c = 0; c < 4; ++c) {
            const float sc = (c == 2) ? SG : SIO;
            const int n = c * 64 + wblk + m;
            const float* s = Whh + n * 64 + 32 + q * 8;
            float4 a = *(const float4*)s;
            float4 b = *(const float4*)(s + 4);
            bf16x8 v;
            v[0] = (__bf16)(sc * a.x); v[1] = (__bf16)(sc * a.y);
            v[2] = (__bf16)(sc * a.z); v[3] = (__bf16)(sc * a.w);
            v[4] = (__bf16)(sc * b.x); v[5] = (__bf16)(sc * b.y);
            v[6] = (__bf16)(sc * b.z); v[7] = (__bf16)(sc * b.w);
            wkt3[(wv * 4 + c) * 64 + lane] = v;
        }
    };
    load_bfr(Wih_e, Whh_e);
    fill_wkt3(Whh_e);

    // c-state: idx = chunk*2 + sub; row = chunk*32 + sub*16 + m, cols wblk + q*4 + r
    f32x4 cst[4];
    #pragma unroll
    for (int i = 0; i < 4; ++i) cst[i] = f32x4{0.f, 0.f, 0.f, 0.f};

    __syncthreads();

    f32x4 acc[2][4];   // [sub][gate] — single set, reused across chunks

    auto gemm = [&](int chunk, const float* bfrag) {
        #pragma unroll
        for (int c = 0; c < 4; ++c) {
            f32x4 b = *(const f32x4*)&bfrag[(wv * 4 + c) * 16 + q * 4];  // quad-broadcast
            acc[0][c] = b;
            acc[1][c] = b;
        }
        #pragma unroll
        for (int kt = 0; kt < 3; ++kt) {
            bf16x8 af0 = *(const bf16x8*)&As[(chunk * 32 + m) * AST + kt * 32 + q * 8];
            bf16x8 af1 = *(const bf16x8*)&As[(chunk * 32 + 16 + m) * AST + kt * 32 + q * 8];
            #pragma unroll
            for (int c = 0; c < 4; ++c) {
                acc[0][c] = __builtin_amdgcn_mfma_f32_16x16x32_bf16(bfr[c][kt], af0, acc[0][c], 0, 0, 0);
                acc[1][c] = __builtin_amdgcn_mfma_f32_16x16x32_bf16(bfr[c][kt], af1, acc[1][c], 0, 0, 0);
            }
        }
        {   // kt = 3: weight frag from LDS, per-c to cap live registers
            bf16x8 af0 = *(const bf16x8*)&As[(chunk * 32 + m) * AST + 96 + q * 8];
            bf16x8 af1 = *(const bf16x8*)&As[(chunk * 32 + 16 + m) * AST + 96 + q * 8];
            #pragma unroll
            for (int c = 0; c < 4; ++c) {
                bf16x8 w3 = wkt3[(wv * 4 + c) * 64 + lane];
                acc[0][c] = __builtin_amdgcn_mfma_f32_16x16x32_bf16(w3, af0, acc[0][c], 0, 0, 0);
                acc[1][c] = __builtin_amdgcn_mfma_f32_16x16x32_bf16(w3, af1, acc[1][c], 0, 0, 0);
            }
        }
    };

    // cell update: 5 exp + 3 rcp per cell (prescaled gates, shared-rcp identity)
    auto update = [&](int chunk) {
        #pragma unroll
        for (int sub = 0; sub < 2; ++sub) {
            const int idx = chunk * 2 + sub;
            const int row = chunk * 32 + sub * 16 + m;
            f32x4 ci = cst[idx];
            bf16x4 h4;
            #pragma unroll
            for (int r = 0; r < 4; ++r) {
                const float gi = acc[sub][0][r];
                const float gf = acc[sub][1][r];
                const float gg = acc[sub][2][r];
                const float go = acc[sub][3][r];
                const float Ef = exp2_(gf);                 // exp(-f)
                const float a  = ci[r] * rcp_(1.0f + Ef);   // sigmoid(f)*c
                const float Ei = exp2_(gi);                 // exp(-i)
                const float Eg = exp2_(gg);                 // exp(2g)
                const float d1 = 1.0f + Ei;
                const float r1 = rcp_(fmaf(d1, Eg, d1));    // 1/[(1+Ei)(1+Eg)]
                const float cN = fmaf(Eg - 1.0f, r1, a);
                const float Eo = exp2_(go);                 // exp(-o)
                const float Ec = exp2_(cN * SG);            // exp(2c)
                const float d2 = 1.0f + Eo;
                const float r2 = rcp_(fmaf(d2, Ec, d2));
                const float h  = (Ec - 1.0f) * r2;          // sig(o)*tanh(cN)
                ci[r] = cN;
                h4[r] = (__bf16)h;
            }
            cst[idx] = ci;
            *(bf16x4*)&As[row * AST + 64 + wblk + q * 4] = h4;
        }
    };

    // emb for one 32-row chunk: row = chunk*32 + (lane&31), half-octet by lane>>5
    auto emb_chunk = [&](int chunk, float o0, float o1) {
        const int row = chunk * 32 + (lane & 31);
        const int h8  = lane >> 5;
        bf16x8 v;
        #pragma unroll
        for (int j = 0; j < 8; ++j) {
            float4 wc = sw.embc[wblk + h8 * 8 + j];
            v[j] = (__bf16)fmaxf(fmaf(o0, wc.x, fmaf(o1, wc.y, wc.z)), 0.f);
        }
        *(bf16x8*)&As[row * AST + wblk + h8 * 8] = v;
    };

    const float* obr = obs + (gRow0 + (lane & 31)) * (OBS * 2);   // chunk0 row; chunk1 = +32 rows

    // prologue: x0 for both chunks, then gemm(c0)
    {
        f32x2 o0 = *(const f32x2*)obr;
        f32x2 o1 = *(const f32x2*)(obr + 32 * (OBS * 2));
        emb_chunk(0, o0[0], o0[1]);
        emb_chunk(1, o1[0], o1[1]);
    }
    __syncthreads();
    gemm(0, sw.biasf_e);

    // ================= encoder (2 barriers/step) =================
    for (int t = 0; t < OBS; ++t) {
        __syncthreads();                               // ph A
        f32x2 on0{0.f, 0.f};
        if (t + 1 < OBS) on0 = *(const f32x2*)(obr + (t + 1) * 2);
        update(0);                                     // h(t, c0)
        gemm(1, sw.biasf_e);                           // gates(c1, t)
        if (t + 1 < OBS) emb_chunk(0, on0[0], on0[1]); // x(t+1, c0)
        __syncthreads();                               // ph B
        f32x2 on1{0.f, 0.f};
        if (t + 1 < OBS) on1 = *(const f32x2*)(obr + 32 * (OBS * 2) + (t + 1) * 2);
        update(1);                                     // h(t, c1)
        if (t + 1 < OBS) {
            gemm(0, sw.biasf_e);                       // gates(c0, t+1)
            emb_chunk(1, on1[0], on1[1]);              // x(t+1, c1)
        }
    }
    // As.x holds emb(obs[:,19]) == dec_in; h,c carry over.

    // ================= decoder =================
    load_bfr(Wih_d, Whh_d);
    fill_wkt3(Whh_d);     // wave-local slice; all enc reads finished before ph B's barrier
    gemm(0, sw.biasf_d);  // td=0, c0

    auto pred_phase = [&](int chunk, int td) {
        const int row  = chunk * 32 + (tid >> 3);
        const int comp = (tid >> 2) & 1;
        const int seg  = tid & 3;
        bf16x8 h0 = *(const bf16x8*)&As[row * AST + 64 + seg * 16];
        bf16x8 h1 = *(const bf16x8*)&As[row * AST + 64 + seg * 16 + 8];
        f32x4 w0 = *(const f32x4*)&sw.wfc[comp * 64 + seg * 16];
        f32x4 w1 = *(const f32x4*)&sw.wfc[comp * 64 + seg * 16 + 4];
        f32x4 w2 = *(const f32x4*)&sw.wfc[comp * 64 + seg * 16 + 8];
        f32x4 w3 = *(const f32x4*)&sw.wfc[comp * 64 + seg * 16 + 12];
        float p = (float)h0[0] * w0[0] + (float)h0[1] * w0[1] + (float)h0[2] * w0[2] + (float)h0[3] * w0[3]
                + (float)h0[4] * w1[0] + (float)h0[5] * w1[1] + (float)h0[6] * w1[2] + (float)h0[7] * w1[3]
                + (float)h1[0] * w2[0] + (float)h1[1] * w2[1] + (float)h1[2] * w2[2] + (float)h1[3] * w2[3]
                + (float)h1[4] * w3[0] + (float)h1[5] * w3[1] + (float)h1[6] * w3[2] + (float)h1[7] * w3[3];
        p += __shfl_xor(p, 1, 64);
        p += __shfl_xor(p, 2, 64);
        if (seg == 0) {
            p += sw.bfc[comp];
            pred_s[row * 2 + comp] = p;
            out[((gRow0 + row) * PRED + td) * 2 + comp] = p;
        }
    };
    auto emb_dec = [&](int chunk) {
        const int row = chunk * 32 + (lane & 31);
        f32x2 pv = *(const f32x2*)&pred_s[row * 2];
        emb_chunk(chunk, pv[0], pv[1]);
    };

    for (int td = 0; td < PRED; ++td) {
        __syncthreads();                 // ph1
        update(0);                       // h(td, c0)
        gemm(1, sw.biasf_d);             // gates(c1, td)
        __syncthreads();                 // ph2
        update(1);                       // h(td, c1)
        pred_phase(0, td);
        __syncthreads();                 // ph3
        pred_phase(1, td);
        if (td + 1 < PRED) emb_dec(0);   // x(td+1, c0)
        __syncthreads();                 // ph4
        if (td + 1 < PRED) {
            emb_dec(1);                  // x(td+1, c1)
            gemm(0, sw.biasf_d);         // gates(c0, td+1)
        }
    }
}

extern "C" void kernel_launch(void* const* d_in, const int* in_sizes, int n_in,
                              void* d_out, int out_size, void* d_ws, size_t ws_size,
                              hipStream_t stream) {
    (void)in_sizes; (void)n_in; (void)d_ws; (void)ws_size; (void)out_size;
    const float* obs   = (const float*)d_in[0];
    const float* W_emb = (const float*)d_in[1];
    const float* b_emb = (const float*)d_in[2];
    const float* Wih_e = (const float*)d_in[3];
    const float* Whh_e = (const float*)d_in[4];
    const float* bih_e = (const float*)d_in[5];
    const float* bhh_e = (const float*)d_in[6];
    const float* Wih_d = (const float*)d_in[7];
    const float* Whh_d = (const float*)d_in[8];
    const float* bih_d = (const float*)d_in[9];
    const float* bhh_d = (const float*)d_in[10];
    const float* W_fc  = (const float*)d_in[11];
    const float* b_fc  = (const float*)d_in[12];
    float* o = (float*)d_out;

    dim3 grid(BATCH / BT), block(256);
    hipLaunchKernelGGL(vanilla_lstm, grid, block, 0, stream,
                       obs, W_emb, b_emb, Wih_e, Whh_e, bih_e, bhh_e,
                       Wih_d, Whh_d, bih_d, bhh_d, W_fc, b_fc, o);
}

// Round 8
// 282.730 us; speedup vs baseline: 1.1130x; 1.1130x over previous
//
#include <hip/hip_runtime.h>

typedef __bf16 bf16x8 __attribute__((ext_vector_type(8)));
typedef __bf16 bf16x4 __attribute__((ext_vector_type(4)));
typedef float  f32x4  __attribute__((ext_vector_type(4)));
typedef float  f32x2  __attribute__((ext_vector_type(2)));

constexpr int BATCH = 65536;
constexpr int OBS   = 20;
constexpr int PRED  = 12;
constexpr int BT    = 64;    // batch rows per workgroup -> grid 1024
constexpr int AST   = 136;   // A-row stride in bf16 elems

// gate pre-scales folded into weights/biases:
// i,f,o scaled by -log2(e)  -> sigmoid(x) = rcp(1 + exp2(gate))
// g     scaled by +2*log2(e)-> tanh(x)    = (exp2(gate)-1)/(exp2(gate)+1)
constexpr float SIO = -1.4426950408889634f;
constexpr float SG  =  2.8853900817779268f;

__device__ __forceinline__ float exp2_(float x) { return __builtin_amdgcn_exp2f(x); }
__device__ __forceinline__ float rcp_(float x)  { return __builtin_amdgcn_rcpf(x); }

struct SmallW {
    float  biasf_e[256];  // prescaled, fragment-ordered: [(wv*4+c)*16 + q*4 + r]
    float  biasf_d[256];
    float4 embc[64];      // {w_emb[e][0], w_emb[e][1], b_emb[e], 0}
    float  wfc[128];      // W_fc [2][64]
    float  bfc[2];
};

__global__ __launch_bounds__(256, 3)
void vanilla_lstm(const float* __restrict__ obs,
                  const float* __restrict__ W_emb, const float* __restrict__ b_emb,
                  const float* __restrict__ Wih_e, const float* __restrict__ Whh_e,
                  const float* __restrict__ bih_e, const float* __restrict__ bhh_e,
                  const float* __restrict__ Wih_d, const float* __restrict__ Whh_d,
                  const float* __restrict__ bih_d, const float* __restrict__ bhh_d,
                  const float* __restrict__ W_fc,  const float* __restrict__ b_fc,
                  float* __restrict__ out)
{
    __shared__ __align__(16) __bf16 As[BT * AST];   // [x(64) | h(64)] bf16, padded
    __shared__ bf16x8 wkt3[1024];                   // Whh cols 32..63, fragment-ordered, 16 KB
    __shared__ __align__(16) float  pred_s[BT * 2];
    __shared__ SmallW sw;

    const int tid  = threadIdx.x;
    const int wv   = tid >> 6;
    const int lane = tid & 63;
    const int m    = lane & 15;
    const int q    = lane >> 4;
    const int wblk = wv * 16;          // this wave's 16 hidden cols
    const size_t gRow0 = (size_t)blockIdx.x * BT;

    // ---- stage small weights ----
    {
        const int wv_ = tid >> 6, c_ = (tid >> 4) & 3, qr = tid & 15;
        const int g = c_ * 64 + wv_ * 16 + qr;
        const float sc = (c_ == 2) ? SG : SIO;
        sw.biasf_e[tid] = sc * (bih_e[g] + bhh_e[g]);
        sw.biasf_d[tid] = sc * (bih_d[g] + bhh_d[g]);
    }
    if (tid < 64)  sw.embc[tid] = make_float4(W_emb[2 * tid], W_emb[2 * tid + 1], b_emb[tid], 0.f);
    if (tid < 128) sw.wfc[tid]  = W_fc[tid];
    if (tid < 2)   sw.bfc[tid]  = b_fc[tid];

    // ---- zero As (h half must start at 0) ----
    {
        uint4 z; z.x = z.y = z.z = z.w = 0u;
        uint4* p = (uint4*)As;
        constexpr int NV = BT * AST * 2 / 16;   // 1088
        #pragma unroll
        for (int i = 0; i < NV / 256; ++i) p[tid + i * 256] = z;
        if (tid < (NV % 256)) p[tid + (NV / 256) * 256] = z;
    }

    // ---- weight fragments: kt 0..2 in regs, kt 3 in LDS (wave-local slice) ----
    bf16x8 bfr[4][3];
    auto load_bfr = [&](const float* Wih, const float* Whh) {
        #pragma unroll
        for (int c = 0; c < 4; ++c) {
            const float sc = (c == 2) ? SG : SIO;
            const int n = c * 64 + wblk + m;
            #pragma unroll
            for (int kt = 0; kt < 3; ++kt) {
                const float* s = (kt < 2) ? (Wih + n * 64 + kt * 32 + q * 8)
                                          : (Whh + n * 64 + q * 8);
                float4 a = *(const float4*)s;
                float4 b = *(const float4*)(s + 4);
                bf16x8 v;
                v[0] = (__bf16)(sc * a.x); v[1] = (__bf16)(sc * a.y);
                v[2] = (__bf16)(sc * a.z); v[3] = (__bf16)(sc * a.w);
                v[4] = (__bf16)(sc * b.x); v[5] = (__bf16)(sc * b.y);
                v[6] = (__bf16)(sc * b.z); v[7] = (__bf16)(sc * b.w);
                bfr[c][kt] = v;
            }
        }
    };
    auto fill_wkt3 = [&](const float* Whh) {   // wave-local slice only -> no cross-wave hazard
        #pragma unroll
        for (int c = 0; c < 4; ++c) {
            const float sc = (c == 2) ? SG : SIO;
            const int n = c * 64 + wblk + m;
            const float* s = Whh + n * 64 + 32 + q * 8;
            float4 a = *(const float4*)s;
            float4 b = *(const float4*)(s + 4);
            bf16x8 v;
            v[0] = (__bf16)(sc * a.x); v[1] = (__bf16)(sc * a.y);
            v[2] = (__bf16)(sc * a.z); v[3] = (__bf16)(sc * a.w);
            v[4] = (__bf16)(sc * b.x); v[5] = (__bf16)(sc * b.y);
            v[6] = (__bf16)(sc * b.z); v[7] = (__bf16)(sc * b.w);
            wkt3[(wv * 4 + c) * 64 + lane] = v;
        }
    };
    load_bfr(Wih_e, Whh_e);
    fill_wkt3(Whh_e);

    // c-state: idx = chunk*2 + sub; row = chunk*32 + sub*16 + m, cols wblk + q*4 + r
    f32x4 cst[4];
    #pragma unroll
    for (int i = 0; i < 4; ++i) cst[i] = f32x4{0.f, 0.f, 0.f, 0.f};

    __syncthreads();

    f32x4 acc[2][4];   // [sub][gate] — single set, reused across chunks

    auto gemm = [&](int chunk, const float* bfrag) {
        #pragma unroll
        for (int c = 0; c < 4; ++c) {
            f32x4 b = *(const f32x4*)&bfrag[(wv * 4 + c) * 16 + q * 4];  // quad-broadcast
            acc[0][c] = b;
            acc[1][c] = b;
        }
        #pragma unroll
        for (int kt = 0; kt < 3; ++kt) {
            bf16x8 af0 = *(const bf16x8*)&As[(chunk * 32 + m) * AST + kt * 32 + q * 8];
            bf16x8 af1 = *(const bf16x8*)&As[(chunk * 32 + 16 + m) * AST + kt * 32 + q * 8];
            #pragma unroll
            for (int c = 0; c < 4; ++c) {
                acc[0][c] = __builtin_amdgcn_mfma_f32_16x16x32_bf16(bfr[c][kt], af0, acc[0][c], 0, 0, 0);
                acc[1][c] = __builtin_amdgcn_mfma_f32_16x16x32_bf16(bfr[c][kt], af1, acc[1][c], 0, 0, 0);
            }
        }
        {   // kt = 3: weight frag from LDS, per-c to cap live registers
            bf16x8 af0 = *(const bf16x8*)&As[(chunk * 32 + m) * AST + 96 + q * 8];
            bf16x8 af1 = *(const bf16x8*)&As[(chunk * 32 + 16 + m) * AST + 96 + q * 8];
            #pragma unroll
            for (int c = 0; c < 4; ++c) {
                bf16x8 w3 = wkt3[(wv * 4 + c) * 64 + lane];
                acc[0][c] = __builtin_amdgcn_mfma_f32_16x16x32_bf16(w3, af0, acc[0][c], 0, 0, 0);
                acc[1][c] = __builtin_amdgcn_mfma_f32_16x16x32_bf16(w3, af1, acc[1][c], 0, 0, 0);
            }
        }
    };

    // cell update: 5 exp + 3 rcp per cell (prescaled gates, shared-rcp identity)
    auto update = [&](int chunk) {
        #pragma unroll
        for (int sub = 0; sub < 2; ++sub) {
            const int idx = chunk * 2 + sub;
            const int row = chunk * 32 + sub * 16 + m;
            f32x4 ci = cst[idx];
            bf16x4 h4;
            #pragma unroll
            for (int r = 0; r < 4; ++r) {
                const float gi = acc[sub][0][r];
                const float gf = acc[sub][1][r];
                const float gg = acc[sub][2][r];
                const float go = acc[sub][3][r];
                const float Ef = exp2_(gf);                 // exp(-f)
                const float a  = ci[r] * rcp_(1.0f + Ef);   // sigmoid(f)*c
                const float Ei = exp2_(gi);                 // exp(-i)
                const float Eg = exp2_(gg);                 // exp(2g)
                const float d1 = 1.0f + Ei;
                const float r1 = rcp_(fmaf(d1, Eg, d1));    // 1/[(1+Ei)(1+Eg)]
                const float cN = fmaf(Eg - 1.0f, r1, a);
                const float Eo = exp2_(go);                 // exp(-o)
                const float Ec = exp2_(cN * SG);            // exp(2c)
                const float d2 = 1.0f + Eo;
                const float r2 = rcp_(fmaf(d2, Ec, d2));
                const float h  = (Ec - 1.0f) * r2;          // sig(o)*tanh(cN)
                ci[r] = cN;
                h4[r] = (__bf16)h;
            }
            cst[idx] = ci;
            *(bf16x4*)&As[row * AST + 64 + wblk + q * 4] = h4;
        }
    };

    // emb for one 32-row chunk: row = chunk*32 + (lane&31), half-octet by lane>>5
    auto emb_chunk = [&](int chunk, float o0, float o1) {
        const int row = chunk * 32 + (lane & 31);
        const int h8  = lane >> 5;
        bf16x8 v;
        #pragma unroll
        for (int j = 0; j < 8; ++j) {
            float4 wc = sw.embc[wblk + h8 * 8 + j];
            v[j] = (__bf16)fmaxf(fmaf(o0, wc.x, fmaf(o1, wc.y, wc.z)), 0.f);
        }
        *(bf16x8*)&As[row * AST + wblk + h8 * 8] = v;
    };

    const float* obr = obs + (gRow0 + (lane & 31)) * (OBS * 2);   // chunk0 row; chunk1 = +32 rows

    // prologue: x0 for both chunks, then gemm(c0)
    {
        f32x2 o0 = *(const f32x2*)obr;
        f32x2 o1 = *(const f32x2*)(obr + 32 * (OBS * 2));
        emb_chunk(0, o0[0], o0[1]);
        emb_chunk(1, o1[0], o1[1]);
    }
    __syncthreads();
    gemm(0, sw.biasf_e);

    // ================= encoder (2 barriers/step) =================
    for (int t = 0; t < OBS; ++t) {
        __syncthreads();                               // ph A
        f32x2 on0{0.f, 0.f};
        if (t + 1 < OBS) on0 = *(const f32x2*)(obr + (t + 1) * 2);
        update(0);                                     // h(t, c0)
        gemm(1, sw.biasf_e);                           // gates(c1, t)
        if (t + 1 < OBS) emb_chunk(0, on0[0], on0[1]); // x(t+1, c0)
        __syncthreads();                               // ph B
        f32x2 on1{0.f, 0.f};
        if (t + 1 < OBS) on1 = *(const f32x2*)(obr + 32 * (OBS * 2) + (t + 1) * 2);
        update(1);                                     // h(t, c1)
        if (t + 1 < OBS) {
            gemm(0, sw.biasf_e);                       // gates(c0, t+1)
            emb_chunk(1, on1[0], on1[1]);              // x(t+1, c1)
        }
    }
    // As.x holds emb(obs[:,19]) == dec_in; h,c carry over.

    // ================= decoder =================
    load_bfr(Wih_d, Whh_d);
    fill_wkt3(Whh_d);     // wave-local slice; all enc reads finished before ph B's barrier
    gemm(0, sw.biasf_d);  // td=0, c0

    auto pred_phase = [&](int chunk, int td) {
        const int row  = chunk * 32 + (tid >> 3);
        const int comp = (tid >> 2) & 1;
        const int seg  = tid & 3;
        bf16x8 h0 = *(const bf16x8*)&As[row * AST + 64 + seg * 16];
        bf16x8 h1 = *(const bf16x8*)&As[row * AST + 64 + seg * 16 + 8];
        f32x4 w0 = *(const f32x4*)&sw.wfc[comp * 64 + seg * 16];
        f32x4 w1 = *(const f32x4*)&sw.wfc[comp * 64 + seg * 16 + 4];
        f32x4 w2 = *(const f32x4*)&sw.wfc[comp * 64 + seg * 16 + 8];
        f32x4 w3 = *(const f32x4*)&sw.wfc[comp * 64 + seg * 16 + 12];
        float p = (float)h0[0] * w0[0] + (float)h0[1] * w0[1] + (float)h0[2] * w0[2] + (float)h0[3] * w0[3]
                + (float)h0[4] * w1[0] + (float)h0[5] * w1[1] + (float)h0[6] * w1[2] + (float)h0[7] * w1[3]
                + (float)h1[0] * w2[0] + (float)h1[1] * w2[1] + (float)h1[2] * w2[2] + (float)h1[3] * w2[3]
                + (float)h1[4] * w3[0] + (float)h1[5] * w3[1] + (float)h1[6] * w3[2] + (float)h1[7] * w3[3];
        p += __shfl_xor(p, 1, 64);
        p += __shfl_xor(p, 2, 64);
        if (seg == 0) {
            p += sw.bfc[comp];
            pred_s[row * 2 + comp] = p;
            out[((gRow0 + row) * PRED + td) * 2 + comp] = p;
        }
    };
    auto emb_dec = [&](int chunk) {
        const int row = chunk * 32 + (lane & 31);
        f32x2 pv = *(const f32x2*)&pred_s[row * 2];
        emb_chunk(chunk, pv[0], pv[1]);
    };

    for (int td = 0; td < PRED; ++td) {
        __syncthreads();                 // ph1
        update(0);                       // h(td, c0)
        gemm(1, sw.biasf_d);             // gates(c1, td)
        __syncthreads();                 // ph2
        update(1);                       // h(td, c1)
        pred_phase(0, td);
        __syncthreads();                 // ph3
        pred_phase(1, td);
        if (td + 1 < PRED) emb_dec(0);   // x(td+1, c0)
        __syncthreads();                 // ph4
        if (td + 1 < PRED) {
            emb_dec(1);                  // x(td+1, c1)
            gemm(0, sw.biasf_d);         // gates(c0, td+1)
        }
    }
}

extern "C" void kernel_launch(void* const* d_in, const int* in_sizes, int n_in,
                              void* d_out, int out_size, void* d_ws, size_t ws_size,
                              hipStream_t stream) {
    (void)in_sizes; (void)n_in; (void)d_ws; (void)ws_size; (void)out_size;
    const float* obs   = (const float*)d_in[0];
    const float* W_emb = (const float*)d_in[1];
    const float* b_emb = (const float*)d_in[2];
    const float* Wih_e = (const float*)d_in[3];
    const float* Whh_e = (const float*)d_in[4];
    const float* bih_e = (const float*)d_in[5];
    const float* bhh_e = (const float*)d_in[6];
    const float* Wih_d = (const float*)d_in[7];
    const float* Whh_d = (const float*)d_in[8];
    const float* bih_d = (const float*)d_in[9];
    const float* bhh_d = (const float*)d_in[10];
    const float* W_fc  = (const float*)d_in[11];
    const float* b_fc  = (const float*)d_in[12];
    float* o = (float*)d_out;

    dim3 grid(BATCH / BT), block(256);
    hipLaunchKernelGGL(vanilla_lstm, grid, block, 0, stream,
                       obs, W_emb, b_emb, Wih_e, Whh_e, bih_e, bhh_e,
                       Wih_d, Whh_d, bih_d, bhh_d, W_fc, b_fc, o);
}

// Round 9
// 278.413 us; speedup vs baseline: 1.1302x; 1.0155x over previous
//
#include <hip/hip_runtime.h>

typedef __bf16 bf16x8 __attribute__((ext_vector_type(8)));
typedef __bf16 bf16x4 __attribute__((ext_vector_type(4)));
typedef float  f32x4  __attribute__((ext_vector_type(4)));
typedef float  f32x2  __attribute__((ext_vector_type(2)));

constexpr int OBS   = 20;
constexpr int PRED  = 12;
constexpr int AST   = 136;   // A-row stride in bf16 elems
constexpr int NBIG  = 512;   // blocks with 96 rows (NSUB=3)
constexpr int GRID  = 768;   // = 3 * 256 CUs -> perfectly packed at 3 blocks/CU
// 512*96 + 256*64 = 65536 rows total

// gate pre-scales folded into weights/biases:
// i,f,o scaled by -log2(e)  -> sigmoid(x) = rcp(1 + exp2(gate))
// g     scaled by +2*log2(e)-> tanh(x)    = (exp2(gate)-1)/(exp2(gate)+1)
constexpr float SIO = -1.4426950408889634f;
constexpr float SG  =  2.8853900817779268f;

__device__ __forceinline__ float exp2_(float x) { return __builtin_amdgcn_exp2f(x); }
__device__ __forceinline__ float rcp_(float x)  { return __builtin_amdgcn_rcpf(x); }

struct SmallW {
    float  biasf_e[256];  // prescaled, fragment-ordered: [(wv*4+c)*16 + q*4 + r]
    float  biasf_d[256];
    float4 embc[64];      // {w_emb[e][0], w_emb[e][1], b_emb[e], 0}
    float  wfc[128];      // W_fc [2][64]
    float  bfc[2];
};

__device__ __forceinline__ void load_bfr(bf16x8 (&bfr)[4][3],
                                         const float* Wih, const float* Whh,
                                         int wblk, int m, int q) {
    #pragma unroll
    for (int c = 0; c < 4; ++c) {
        const float sc = (c == 2) ? SG : SIO;
        const int n = c * 64 + wblk + m;
        #pragma unroll
        for (int kt = 0; kt < 3; ++kt) {
            const float* s = (kt < 2) ? (Wih + n * 64 + kt * 32 + q * 8)
                                      : (Whh + n * 64 + q * 8);
            float4 a = *(const float4*)s;
            float4 b = *(const float4*)(s + 4);
            bf16x8 v;
            v[0] = (__bf16)(sc * a.x); v[1] = (__bf16)(sc * a.y);
            v[2] = (__bf16)(sc * a.z); v[3] = (__bf16)(sc * a.w);
            v[4] = (__bf16)(sc * b.x); v[5] = (__bf16)(sc * b.y);
            v[6] = (__bf16)(sc * b.z); v[7] = (__bf16)(sc * b.w);
            bfr[c][kt] = v;
        }
    }
}

// Whh cols 32..63 fragment into LDS; wave-local slice (each wave writes exactly
// the entries its own gemm reads) -> no cross-wave hazard on refill.
__device__ __forceinline__ void fill_wkt3(bf16x8* wkt3, const float* Whh,
                                          int wv, int lane, int wblk, int m, int q) {
    #pragma unroll
    for (int c = 0; c < 4; ++c) {
        const float sc = (c == 2) ? SG : SIO;
        const int n = c * 64 + wblk + m;
        const float* s = Whh + n * 64 + 32 + q * 8;
        float4 a = *(const float4*)s;
        float4 b = *(const float4*)(s + 4);
        bf16x8 v;
        v[0] = (__bf16)(sc * a.x); v[1] = (__bf16)(sc * a.y);
        v[2] = (__bf16)(sc * a.z); v[3] = (__bf16)(sc * a.w);
        v[4] = (__bf16)(sc * b.x); v[5] = (__bf16)(sc * b.y);
        v[6] = (__bf16)(sc * b.z); v[7] = (__bf16)(sc * b.w);
        wkt3[(wv * 4 + c) * 64 + lane] = v;
    }
}

// NSUB = sub-tiles (16 rows each) per chunk; block covers 2 chunks = NSUB*32 rows.
template<int NSUB>
__device__ void lstm_body(__bf16* As, bf16x8* wkt3, float* pred_s, SmallW& sw,
                          const float* obs,
                          const float* Wih_e, const float* Whh_e,
                          const float* Wih_d, const float* Whh_d,
                          float* out, size_t gRow0)
{
    constexpr int CH = NSUB * 16;        // rows per chunk
    constexpr int NP = (NSUB + 1) / 2;   // 32-row passes per chunk for emb/pred
    const int tid  = threadIdx.x;
    const int wv   = tid >> 6;
    const int lane = tid & 63;
    const int m    = lane & 15;
    const int q    = lane >> 4;
    const int wblk = wv * 16;

    bf16x8 bfr[4][3];
    load_bfr(bfr, Wih_e, Whh_e, wblk, m, q);

    f32x4 cst[2 * NSUB];
    #pragma unroll
    for (int i = 0; i < 2 * NSUB; ++i) cst[i] = f32x4{0.f, 0.f, 0.f, 0.f};

    f32x4 acc[NSUB][4];   // [sub][gate] — single set, reused across chunks

    auto gemm = [&](int chunk, const float* bfrag) {
        #pragma unroll
        for (int c = 0; c < 4; ++c) {
            f32x4 b = *(const f32x4*)&bfrag[(wv * 4 + c) * 16 + q * 4];
            #pragma unroll
            for (int s = 0; s < NSUB; ++s) acc[s][c] = b;
        }
        #pragma unroll
        for (int kt = 0; kt < 3; ++kt) {
            bf16x8 af[NSUB];
            #pragma unroll
            for (int s = 0; s < NSUB; ++s)
                af[s] = *(const bf16x8*)&As[(chunk * CH + s * 16 + m) * AST + kt * 32 + q * 8];
            #pragma unroll
            for (int s = 0; s < NSUB; ++s)
                #pragma unroll
                for (int c = 0; c < 4; ++c)
                    acc[s][c] = __builtin_amdgcn_mfma_f32_16x16x32_bf16(bfr[c][kt], af[s], acc[s][c], 0, 0, 0);
        }
        {   // kt = 3: weight frag from LDS, per-c to cap live registers
            bf16x8 af[NSUB];
            #pragma unroll
            for (int s = 0; s < NSUB; ++s)
                af[s] = *(const bf16x8*)&As[(chunk * CH + s * 16 + m) * AST + 96 + q * 8];
            #pragma unroll
            for (int c = 0; c < 4; ++c) {
                bf16x8 w3 = wkt3[(wv * 4 + c) * 64 + lane];
                #pragma unroll
                for (int s = 0; s < NSUB; ++s)
                    acc[s][c] = __builtin_amdgcn_mfma_f32_16x16x32_bf16(w3, af[s], acc[s][c], 0, 0, 0);
            }
        }
    };

    // cell update: 5 exp + 3 rcp per cell (prescaled gates, shared-rcp identity)
    auto update = [&](int chunk) {
        #pragma unroll
        for (int sub = 0; sub < NSUB; ++sub) {
            const int idx = chunk * NSUB + sub;
            const int row = chunk * CH + sub * 16 + m;
            f32x4 ci = cst[idx];
            bf16x4 h4;
            #pragma unroll
            for (int r = 0; r < 4; ++r) {
                const float gi = acc[sub][0][r];
                const float gf = acc[sub][1][r];
                const float gg = acc[sub][2][r];
                const float go = acc[sub][3][r];
                const float Ef = exp2_(gf);                 // exp(-f)
                const float a  = ci[r] * rcp_(1.0f + Ef);   // sigmoid(f)*c
                const float Ei = exp2_(gi);                 // exp(-i)
                const float Eg = exp2_(gg);                 // exp(2g)
                const float d1 = 1.0f + Ei;
                const float r1 = rcp_(fmaf(d1, Eg, d1));    // 1/[(1+Ei)(1+Eg)]
                const float cN = fmaf(Eg - 1.0f, r1, a);
                const float Eo = exp2_(go);                 // exp(-o)
                const float Ec = exp2_(cN * SG);            // exp(2c)
                const float d2 = 1.0f + Eo;
                const float r2 = rcp_(fmaf(d2, Ec, d2));
                const float h  = (Ec - 1.0f) * r2;          // sig(o)*tanh(cN)
                ci[r] = cN;
                h4[r] = (__bf16)h;
            }
            cst[idx] = ci;
            *(bf16x4*)&As[row * AST + 64 + wblk + q * 4] = h4;
        }
    };

    // emb of step t for one chunk: passes of 32 rows, wave covers its 16 cols
    auto emb_enc = [&](int chunk, int t) {
        const int h8 = lane >> 5;
        #pragma unroll
        for (int p = 0; p < NP; ++p) {
            const int rloc = p * 32 + (lane & 31);
            if (rloc < CH) {
                const int row = chunk * CH + rloc;
                f32x2 ov = *(const f32x2*)(obs + (gRow0 + row) * (OBS * 2) + t * 2);
                bf16x8 v;
                #pragma unroll
                for (int j = 0; j < 8; ++j) {
                    float4 wc = sw.embc[wblk + h8 * 8 + j];
                    v[j] = (__bf16)fmaxf(fmaf(ov[0], wc.x, fmaf(ov[1], wc.y, wc.z)), 0.f);
                }
                *(bf16x8*)&As[row * AST + wblk + h8 * 8] = v;
            }
        }
    };

    __syncthreads();   // staging (sw, h-zero, wkt3) from caller visible to all waves

    // prologue: x(0) for both chunks, then gemm(c0)
    emb_enc(0, 0);
    emb_enc(1, 0);
    __syncthreads();
    gemm(0, sw.biasf_e);

    // ================= encoder (2 barriers/step) =================
    for (int t = 0; t < OBS; ++t) {
        __syncthreads();                       // ph A
        update(0);                             // h(t, c0)
        gemm(1, sw.biasf_e);                   // gates(c1, t)
        if (t + 1 < OBS) emb_enc(0, t + 1);    // x(t+1, c0)
        __syncthreads();                       // ph B
        update(1);                             // h(t, c1)
        if (t + 1 < OBS) {
            gemm(0, sw.biasf_e);               // gates(c0, t+1)
            emb_enc(1, t + 1);                 // x(t+1, c1)
        }
    }
    // As.x holds emb(obs[:,19]) == dec_in; h,c carry over.

    // ================= decoder =================
    load_bfr(bfr, Wih_d, Whh_d, wblk, m, q);
    fill_wkt3(wkt3, Whh_d, wv, lane, wblk, m, q);   // wave-local slice
    gemm(0, sw.biasf_d);                            // td=0, c0

    auto pred_phase = [&](int chunk, int td) {
        const int comp = (tid >> 2) & 1;
        const int seg  = tid & 3;
        #pragma unroll
        for (int p = 0; p < NP; ++p) {
            const int rloc = p * 32 + (tid >> 3);
            const int row  = chunk * CH + rloc;
            const bool act = (rloc < CH);
            float pv = 0.f;
            if (act) {
                bf16x8 h0 = *(const bf16x8*)&As[row * AST + 64 + seg * 16];
                bf16x8 h1 = *(const bf16x8*)&As[row * AST + 64 + seg * 16 + 8];
                f32x4 w0 = *(const f32x4*)&sw.wfc[comp * 64 + seg * 16];
                f32x4 w1 = *(const f32x4*)&sw.wfc[comp * 64 + seg * 16 + 4];
                f32x4 w2 = *(const f32x4*)&sw.wfc[comp * 64 + seg * 16 + 8];
                f32x4 w3 = *(const f32x4*)&sw.wfc[comp * 64 + seg * 16 + 12];
                pv = (float)h0[0] * w0[0] + (float)h0[1] * w0[1] + (float)h0[2] * w0[2] + (float)h0[3] * w0[3]
                   + (float)h0[4] * w1[0] + (float)h0[5] * w1[1] + (float)h0[6] * w1[2] + (float)h0[7] * w1[3]
                   + (float)h1[0] * w2[0] + (float)h1[1] * w2[1] + (float)h1[2] * w2[2] + (float)h1[3] * w2[3]
                   + (float)h1[4] * w3[0] + (float)h1[5] * w3[1] + (float)h1[6] * w3[2] + (float)h1[7] * w3[3];
            }
            pv += __shfl_xor(pv, 1, 64);   // activity uniform within each 8-lane row group
            pv += __shfl_xor(pv, 2, 64);
            if (act && seg == 0) {
                pv += sw.bfc[comp];
                pred_s[row * 2 + comp] = pv;
                out[((gRow0 + row) * PRED + td) * 2 + comp] = pv;
            }
        }
    };
    auto emb_dec = [&](int chunk) {
        const int h8 = lane >> 5;
        #pragma unroll
        for (int p = 0; p < NP; ++p) {
            const int rloc = p * 32 + (lane & 31);
            if (rloc < CH) {
                const int row = chunk * CH + rloc;
                f32x2 pv = *(const f32x2*)&pred_s[row * 2];
                bf16x8 v;
                #pragma unroll
                for (int j = 0; j < 8; ++j) {
                    float4 wc = sw.embc[wblk + h8 * 8 + j];
                    v[j] = (__bf16)fmaxf(fmaf(pv[0], wc.x, fmaf(pv[1], wc.y, wc.z)), 0.f);
                }
                *(bf16x8*)&As[row * AST + wblk + h8 * 8] = v;
            }
        }
    };

    for (int td = 0; td < PRED; ++td) {
        __syncthreads();                 // ph1
        update(0);                       // h(td, c0)
        gemm(1, sw.biasf_d);             // gates(c1, td)
        __syncthreads();                 // ph2
        update(1);                       // h(td, c1)
        pred_phase(0, td);
        __syncthreads();                 // ph3
        pred_phase(1, td);
        if (td + 1 < PRED) emb_dec(0);   // x(td+1, c0)
        __syncthreads();                 // ph4
        if (td + 1 < PRED) {
            emb_dec(1);                  // x(td+1, c1)
            gemm(0, sw.biasf_d);         // gates(c0, td+1)
        }
    }
}

__global__ __launch_bounds__(256, 3)
void vanilla_lstm(const float* __restrict__ obs,
                  const float* __restrict__ W_emb, const float* __restrict__ b_emb,
                  const float* __restrict__ Wih_e, const float* __restrict__ Whh_e,
                  const float* __restrict__ bih_e, const float* __restrict__ bhh_e,
                  const float* __restrict__ Wih_d, const float* __restrict__ Whh_d,
                  const float* __restrict__ bih_d, const float* __restrict__ bhh_d,
                  const float* __restrict__ W_fc,  const float* __restrict__ b_fc,
                  float* __restrict__ out)
{
    __shared__ __align__(16) __bf16 As[96 * AST];     // sized for the big (96-row) blocks
    __shared__ bf16x8 wkt3[1024];                     // Whh cols 32..63, fragment-ordered
    __shared__ __align__(16) float  pred_s[96 * 2];
    __shared__ SmallW sw;

    const int tid = threadIdx.x;

    // ---- stage small weights ----
    {
        const int wv_ = tid >> 6, c_ = (tid >> 4) & 3, qr = tid & 15;
        const int g = c_ * 64 + wv_ * 16 + qr;
        const float sc = (c_ == 2) ? SG : SIO;
        sw.biasf_e[tid] = sc * (bih_e[g] + bhh_e[g]);
        sw.biasf_d[tid] = sc * (bih_d[g] + bhh_d[g]);
    }
    if (tid < 64)  sw.embc[tid] = make_float4(W_emb[2 * tid], W_emb[2 * tid + 1], b_emb[tid], 0.f);
    if (tid < 128) sw.wfc[tid]  = W_fc[tid];
    if (tid < 2)   sw.bfc[tid]  = b_fc[tid];

    // ---- zero h region (cols 64..127) for all 96 rows: 96*8 = 768 uint4 ----
    {
        uint4 z; z.x = z.y = z.z = z.w = 0u;
        #pragma unroll
        for (int i = 0; i < 3; ++i) {
            const int idx = tid + i * 256;     // 0..767
            const int r = idx >> 3, o = idx & 7;
            *((uint4*)&As[r * AST + 64] + o) = z;
        }
    }

    // ---- encoder Whh kt3 slab into LDS ----
    {
        const int wv = tid >> 6, lane = tid & 63, m = lane & 15, q = lane >> 4;
        fill_wkt3(wkt3, Whh_e, wv, lane, wv * 16, m, q);
    }
    // (visibility barrier is at the top of lstm_body)

    const int bid = blockIdx.x;
    if (bid < NBIG) {
        lstm_body<3>(As, wkt3, pred_s, sw, obs, Wih_e, Whh_e, Wih_d, Whh_d,
                     out, (size_t)bid * 96);
    } else {
        lstm_body<2>(As, wkt3, pred_s, sw, obs, Wih_e, Whh_e, Wih_d, Whh_d,
                     out, (size_t)NBIG * 96 + (size_t)(bid - NBIG) * 64);
    }
}

extern "C" void kernel_launch(void* const* d_in, const int* in_sizes, int n_in,
                              void* d_out, int out_size, void* d_ws, size_t ws_size,
                              hipStream_t stream) {
    (void)in_sizes; (void)n_in; (void)d_ws; (void)ws_size; (void)out_size;
    const float* obs   = (const float*)d_in[0];
    const float* W_emb = (const float*)d_in[1];
    const float* b_emb = (const float*)d_in[2];
    const float* Wih_e = (const float*)d_in[3];
    const float* Whh_e = (const float*)d_in[4];
    const float* bih_e = (const float*)d_in[5];
    const float* bhh_e = (const float*)d_in[6];
    const float* Wih_d = (const float*)d_in[7];
    const float* Whh_d = (const float*)d_in[8];
    const float* bih_d = (const float*)d_in[9];
    const float* bhh_d = (const float*)d_in[10];
    const float* W_fc  = (const float*)d_in[11];
    const float* b_fc  = (const float*)d_in[12];
    float* o = (float*)d_out;

    dim3 grid(GRID), block(256);
    hipLaunchKernelGGL(vanilla_lstm, grid, block, 0, stream,
                       obs, W_emb, b_emb, Wih_e, Whh_e, bih_e, bhh_e,
                       Wih_d, Whh_d, bih_d, bhh_d, W_fc, b_fc, o);
}